// Round 12
// baseline (121.110 us; speedup 1.0000x reference)
//
#include <hip/hip_runtime.h>
#include <hip/hip_bf16.h>
#include <stdint.h>

#define N_NODES 8192
#define IN_F    256
#define HD      64
#define NH      2
#define BROWS   32                       // rows per block
#define ALPHA   0.2f

typedef __attribute__((ext_vector_type(8))) short bf16x8s;
typedef __attribute__((ext_vector_type(4))) float f32x4;

// ws layout (bytes)
#define OFF_U      0          // u[h][v][256] f32                   : 4 KB
#define OFF_WFRAG  4096       // W frag-order [8][8][64][8] bf16    : 64 KB
#define OFF_F1     69632      // f1[2][8192] f32                    : 64 KB
#define OFF_F2     135168     // f2[2][8192] f32                    : 64 KB
#define OFF_F2MAX  200704     // f2max[2] f32 (+pad)
#define OFF_G2     200960     // g2b[2][8192] u32 (bf16 g1|ga<<16)  : 64 KB
#define OFF_WHB    332032     // Wh frag-order [2][128][2][4][64][8] bf16 : 2 MB

__device__ __forceinline__ unsigned short f2bf(float x) {
  union { float f; uint32_t u; } c; c.f = x;
  uint32_t r = c.u + 0x7FFFu + ((c.u >> 16) & 1u);   // RNE
  return (unsigned short)(r >> 16);
}
__device__ __forceinline__ short f2bfs(float x) {
  __hip_bfloat16 b = __float2bfloat16(x);
  return __builtin_bit_cast(short, b);
}

// ---------------- kernel 1: u = W·a (f32) + W repacked to B-fragment order (bf16)
__global__ void gat_prep_kernel(const float* __restrict__ W, const float* __restrict__ a,
                                float* __restrict__ u, unsigned short* __restrict__ wfrag)
{
  int idx = blockIdx.x * 256 + threadIdx.x;
  if (idx < 32768) {
    int j = idx & 7, lane = (idx >> 3) & 63, ks = (idx >> 9) & 7, Dt = idx >> 12;
    int k  = ks * 32 + ((lane >> 4) << 3) + j;
    int dp = Dt * 16 + (lane & 15);
    int hh = dp >> 6, d = dp & 63;
    wfrag[idx] = f2bf(W[(size_t)(hh * IN_F + k) * HD + d]);
  } else if (idx < 32768 + NH * 2 * IN_F) {
    int i2 = idx - 32768;
    int i = i2 & 255, v = (i2 >> 8) & 1, h = i2 >> 9;
    const float* Wp = W + (size_t)(h * IN_F + i) * HD;
    const float* ap = a + h * 2 * HD + v * HD;
    float s = 0.f;
    for (int d = 0; d < HD; ++d) s += Wp[d] * ap[d];
    u[(h * 2 + v) * IN_F + i] = s;
  }
}

// ---------------- kernel 2: f1/f2 = h·u, plus packed bf16 exp pairs
__global__ __launch_bounds__(256) void gat_f12_kernel(const float* __restrict__ hmat,
    const float* __restrict__ u, float* __restrict__ f1, float* __restrict__ f2,
    uint32_t* __restrict__ g2b)
{
  int n = blockIdx.x * 4 + (threadIdx.x >> 6);
  int l = threadIdx.x & 63;
  float4 hv = *(const float4*)(hmat + (size_t)n * IN_F + l * 4);
  float s[4];
#pragma unroll
  for (int q = 0; q < 4; ++q) {
    float4 uv = *(const float4*)(u + q * IN_F + l * 4);
    s[q] = hv.x * uv.x + hv.y * uv.y + hv.z * uv.z + hv.w * uv.w;
  }
#pragma unroll
  for (int off = 1; off < 64; off <<= 1) {
#pragma unroll
    for (int q = 0; q < 4; ++q) s[q] += __shfl_xor(s[q], off);
  }
  if (l == 0) {
    f1[n] = s[0];           f2[n] = s[1];
    f1[N_NODES + n] = s[2]; f2[N_NODES + n] = s[3];
    g2b[n]           = (uint32_t)f2bf(__expf(s[1])) | ((uint32_t)f2bf(__expf(ALPHA * s[1])) << 16);
    g2b[N_NODES + n] = (uint32_t)f2bf(__expf(s[3])) | ((uint32_t)f2bf(__expf(ALPHA * s[3])) << 16);
  }
}

// ---------------- kernel 3: per-head max of f2 (softmax stability bound)
__global__ void gat_f2max_kernel(const float* __restrict__ f2, float* __restrict__ f2m)
{
  int h = blockIdx.x;
  float m = -1e30f;
  for (int i = threadIdx.x; i < N_NODES; i += 256) m = fmaxf(m, f2[h * N_NODES + i]);
#pragma unroll
  for (int off = 1; off < 64; off <<= 1) m = fmaxf(m, __shfl_xor(m, off));
  __shared__ float red[4];
  if ((threadIdx.x & 63) == 0) red[threadIdx.x >> 6] = m;
  __syncthreads();
  if (threadIdx.x == 0) f2m[h] = fmaxf(fmaxf(red[0], red[1]), fmaxf(red[2], red[3]));
}

// ---------------- kernel 4: Wh = h @ W' (bf16 MFMA), epilogue in B-frag order
__global__ __launch_bounds__(256) void gat_wh_kernel(const float* __restrict__ hmat,
    const unsigned short* __restrict__ wfrag, unsigned short* __restrict__ whb)
{
  int tid = threadIdx.x;
  int w = tid >> 6, l = tid & 63;
  int n0 = blockIdx.x * 64;
  int row = n0 + w * 16 + (l & 15);
  f32x4 acc[8] = {};
#pragma unroll
  for (int ks = 0; ks < 8; ++ks) {
    const float* ap = hmat + (size_t)row * IN_F + ks * 32 + ((l >> 4) << 3);
    float av[8];
    *(float4*)&av[0] = *(const float4*)ap;
    *(float4*)&av[4] = *(const float4*)(ap + 4);
    bf16x8s af;
#pragma unroll
    for (int j = 0; j < 8; ++j) af[j] = f2bfs(av[j]);
#pragma unroll
    for (int Dt = 0; Dt < 8; ++Dt) {
      bf16x8s bfv = *(const bf16x8s*)(wfrag + ((size_t)(Dt * 8 + ks) * 64 + l) * 8);
      acc[Dt] = __builtin_amdgcn_mfma_f32_16x16x32_bf16(af, bfv, acc[Dt], 0, 0, 0);
    }
  }
  int Tm = blockIdx.x;
  int s  = w >> 1;
  int lb = ((w & 1) * 2 + ((l >> 4) >> 1)) * 16 + (l & 15);
  int jh = (l >> 4) & 1;
#pragma unroll
  for (int Dt = 0; Dt < 8; ++Dt) {
    int hh = Dt >> 2, D = Dt & 3;
    ushort4 pk;
    pk.x = f2bf(acc[Dt][0]); pk.y = f2bf(acc[Dt][1]);
    pk.z = f2bf(acc[Dt][2]); pk.w = f2bf(acc[Dt][3]);
    size_t off = ((((size_t)(hh * 128 + Tm) * 2 + s) * 4 + D) * 64 + lb) * 8 + jh * 4;
    *(ushort4*)(whb + off) = pk;
  }
}

// ---------------- kernel 5: TWO-PHASE fused attn. Phase A: block dense-streams its
// 32x8192 adj slab -> LDS bitmasks (pack-kernel access pattern, 8-deep MLP).
// Phase B: mask-attn, wave=(head,col-quarter) x both 16-row groups; whb direct from
// L2 (each frag read once per block), no loop barriers; in-block reduce + ELU + store.
__global__ __launch_bounds__(512, 2) void gat_attn_kernel(
    const int* __restrict__ adj, const unsigned short* __restrict__ whb,
    const float* __restrict__ f1, const uint32_t* __restrict__ g2b,
    const float* __restrict__ f2max, float* __restrict__ out)
{
  __shared__ unsigned long long maskbuf[BROWS][128];  // 32 KB bitmasks
  __shared__ uint32_t glp[2][N_NODES];                // 64 KB packed G pairs
  __shared__ float redbuf[12288];                     // 48 KB cross-quarter partials
  __shared__ float lsumbuf[8][2][16];                 // 1 KB row denominators

  int tid = threadIdx.x;
  int wv = tid >> 6, l = tid & 63;
  int rb = blockIdx.x * BROWS;

  // stage packed G pairs (whole row, both heads)
  {
    uint4* gd = (uint4*)glp;
    const uint4* gs = (const uint4*)g2b;
#pragma unroll
    for (int i = 0; i < 8; ++i) gd[i * 512 + tid] = gs[i * 512 + tid];
  }

  // ---- Phase A: dense-stream own adj slab -> ballot-pack masks into LDS
#pragma unroll 1
  for (int r = 0; r < 4; ++r) {
    int lrow = wv * 4 + r;
    const int4* src = (const int4*)(adj + (size_t)(rb + lrow) * N_NODES) + l;
#pragma unroll 1
    for (int cc = 0; cc < 4; ++cc) {
      int4 v[8];
#pragma unroll
      for (int u2 = 0; u2 < 8; ++u2) v[u2] = src[(cc * 8 + u2) * 64];
#pragma unroll
      for (int u2 = 0; u2 < 8; ++u2) {
        int c = cc * 8 + u2;
        unsigned long long b0 = __ballot(v[u2].x > 0);
        unsigned long long b1 = __ballot(v[u2].y > 0);
        unsigned long long b2 = __ballot(v[u2].z > 0);
        unsigned long long b3 = __ballot(v[u2].w > 0);
        if (l == 0) {
          ulonglong2* mp = (ulonglong2*)&maskbuf[lrow][c * 4];
          mp[0] = make_ulonglong2(b0, b1);
          mp[1] = make_ulonglong2(b2, b3);
        }
      }
    }
  }
  __syncthreads();                      // masks + glp visible

  // ---- Phase B: wave = (head h, col-quarter q), both 16-row groups
  int h = wv & 1, q = wv >> 1;
  int mtbase = q * 32;                  // 32 tiles of 64 cols = 2048 cols
  int koff = (l >> 4) << 3;

  float E1v[2], Eav[2];
#pragma unroll
  for (int rg = 0; rg < 2; ++rg) {
    float f1v = f1[h * N_NODES + rb + rg * 16 + (l & 15)];
    float tm  = f1v + f2max[h];
    float mrow = fmaxf(tm, ALPHA * tm);
    E1v[rg] = __expf(f1v - mrow);
    Eav[rg] = __expf(ALPHA * f1v - mrow);
  }

  const uint4* wp = (const uint4*)whb + ((size_t)(h * 128 + mtbase) * 8) * 64 + l;

  f32x4 acc[2][4] = {};
  float lsum[2] = {0.f, 0.f};
  unsigned long long cm[2][4];
  uint4 cur[8], nxt[8];
#pragma unroll
  for (int i = 0; i < 8; ++i) cur[i] = wp[i * 64];

#pragma unroll 2
  for (int t = 0; t < 32; ++t) {
    int mt = mtbase + t;
    if ((t & 3) == 0) {                 // refresh 256-col mask chunk for both rows
      int cidx = (mt >> 2) * 4;
      ulonglong2 m00 = *(const ulonglong2*)&maskbuf[l & 15][cidx];
      ulonglong2 m01 = *(const ulonglong2*)&maskbuf[l & 15][cidx + 2];
      ulonglong2 m10 = *(const ulonglong2*)&maskbuf[16 + (l & 15)][cidx];
      ulonglong2 m11 = *(const ulonglong2*)&maskbuf[16 + (l & 15)][cidx + 2];
      cm[0][0] = m00.x; cm[0][1] = m00.y; cm[0][2] = m01.x; cm[0][3] = m01.y;
      cm[1][0] = m10.x; cm[1][1] = m10.y; cm[1][2] = m11.x; cm[1][3] = m11.y;
    }
    if (t + 1 < 32) {                   // prefetch next tile's whb frags
      const uint4* p = wp + (size_t)(t + 1) * 512;
#pragma unroll
      for (int i = 0; i < 8; ++i) nxt[i] = p[i * 64];
    }

    bf16x8s af[2][2];
#pragma unroll
    for (int s = 0; s < 2; ++s) {
      int sh = ((mt & 3) << 4) + (s << 3) + ((l >> 4) << 1);
      const uint4* gp = (const uint4*)&glp[h][(mt << 6) + s * 32 + koff];
      uint32_t gv[8];
      *(uint4*)&gv[0] = gp[0];
      *(uint4*)&gv[4] = gp[1];
#pragma unroll
      for (int rg = 0; rg < 2; ++rg) {
        uint32_t b0 = (uint32_t)(cm[rg][0] >> sh), b1 = (uint32_t)(cm[rg][1] >> sh);
        uint32_t b2 = (uint32_t)(cm[rg][2] >> sh), b3 = (uint32_t)(cm[rg][3] >> sh);
        float ps = 0.f;
#pragma unroll
        for (int j = 0; j < 8; ++j) {
          uint32_t uv = gv[j];
          float g1 = __builtin_bit_cast(float, uv << 16);
          float ga = __builtin_bit_cast(float, uv & 0xffff0000u);
          float v  = fmaxf(E1v[rg] * g1, Eav[rg] * ga);
          uint32_t bb = (j & 3) == 0 ? b0 : (j & 3) == 1 ? b1 : (j & 3) == 2 ? b2 : b3;
          float p = ((bb >> (j >> 2)) & 1) ? v : 0.f;
          ps += p;
          af[rg][s][j] = f2bfs(p);
        }
        lsum[rg] += ps;
      }
    }

#pragma unroll
    for (int s = 0; s < 2; ++s)
#pragma unroll
      for (int D = 0; D < 4; ++D) {
        bf16x8s bfv = __builtin_bit_cast(bf16x8s, cur[s * 4 + D]);
        acc[0][D] = __builtin_amdgcn_mfma_f32_16x16x32_bf16(af[0][s], bfv, acc[0][D], 0, 0, 0);
        acc[1][D] = __builtin_amdgcn_mfma_f32_16x16x32_bf16(af[1][s], bfv, acc[1][D], 0, 0, 0);
      }
#pragma unroll
    for (int i = 0; i < 8; ++i) cur[i] = nxt[i];
  }

  // row-denominator partials: lanes l, l+16, l+32, l+48 share a row
#pragma unroll
  for (int rg = 0; rg < 2; ++rg) {
    float ls = lsum[rg];
    ls += __shfl_xor(ls, 16);
    ls += __shfl_xor(ls, 32);
    if (l < 16) lsumbuf[wv][rg][l] = ls;
  }
  __syncthreads();                      // all quarters done; maskbuf/glp now dead

  // cross-quarter reduce: q>0 write partials, q==0 combines + ELU + store
  if (q > 0) {
    float* rp = &redbuf[(h * 3 + (q - 1)) * 2048];
#pragma unroll
    for (int rg = 0; rg < 2; ++rg)
#pragma unroll
      for (int D = 0; D < 4; ++D)
#pragma unroll
        for (int r = 0; r < 4; ++r)
          rp[rg * 1024 + D * 256 + ((l >> 4) * 4 + r) * 16 + (l & 15)] = acc[rg][D][r];
  }
  __syncthreads();
  if (q == 0) {
    const float* rp = &redbuf[h * 3 * 2048];
#pragma unroll
    for (int rg = 0; rg < 2; ++rg)
#pragma unroll
      for (int D = 0; D < 4; ++D)
#pragma unroll
        for (int r = 0; r < 4; ++r) {
          int rr = (l >> 4) * 4 + r;
          int ri = rg * 1024 + D * 256 + rr * 16 + (l & 15);
          float v = acc[rg][D][r] + rp[ri] + rp[2048 + ri] + rp[4096 + ri];
          float ls = lsumbuf[h][rg][rr] + lsumbuf[2 + h][rg][rr]
                   + lsumbuf[4 + h][rg][rr] + lsumbuf[6 + h][rg][rr];
          float o = v / fmaxf(ls, 1e-30f);
          out[(size_t)(rb + rg * 16 + rr) * (NH * HD) + h * HD + D * 16 + (l & 15)]
              = (o > 0.f) ? o : (__expf(o) - 1.f);
        }
  }
}

extern "C" void kernel_launch(void* const* d_in, const int* in_sizes, int n_in,
                              void* d_out, int out_size, void* d_ws, size_t ws_size,
                              hipStream_t stream)
{
  const float* hmat = (const float*)d_in[0];
  const int*   adj  = (const int*)d_in[1];
  const float* W    = (const float*)d_in[2];
  const float* a    = (const float*)d_in[3];
  float* out = (float*)d_out;
  char* ws = (char*)d_ws;

  float* u             = (float*)(ws + OFF_U);
  unsigned short* wfrg = (unsigned short*)(ws + OFF_WFRAG);
  float* f1            = (float*)(ws + OFF_F1);
  float* f2            = (float*)(ws + OFF_F2);
  float* f2m           = (float*)(ws + OFF_F2MAX);
  uint32_t* g2b        = (uint32_t*)(ws + OFF_G2);
  unsigned short* whb  = (unsigned short*)(ws + OFF_WHB);

  gat_prep_kernel <<<132, 256, 0, stream>>>(W, a, u, wfrg);
  gat_f12_kernel  <<<N_NODES / 4, 256, 0, stream>>>(hmat, u, f1, f2, g2b);
  gat_f2max_kernel<<<NH, 256, 0, stream>>>(f2, f2m);
  gat_wh_kernel   <<<N_NODES / 64, 256, 0, stream>>>(hmat, wfrg, whb);
  gat_attn_kernel <<<N_NODES / BROWS, 512, 0, stream>>>(adj, whb, f1, g2b, f2m, out);
}